// Round 1
// baseline (159.147 us; speedup 1.0000x reference)
//
#include <hip/hip_runtime.h>
#include <math.h>

#define DDIM 2048
#define NEXP 64
#define BM 32
#define BK 64
#define NCH (DDIM / BK)     // 32 chunks
#define THETA 1e-5f
#define MAXFLAG 16384

// ---------------------------------------------------------------------------
// Kernel 1: fused fp32 GEMM (x[M,2048] x W[64,2048]^T) + sigmoid + biased
// top-7 + weights + outputs. Flags near-tie tokens for f64 refine.
// ---------------------------------------------------------------------------
__launch_bounds__(256, 2)
__global__ void gate_main(const float* __restrict__ x, const float* __restrict__ W,
                          const float* __restrict__ gb, float* __restrict__ out,
                          int* __restrict__ wsc, int M) {
    __shared__ __align__(16) float xs[BK * BM];   // k-major, pair-swizzled: [kk][32 tokens]
    __shared__ __align__(16) float wsh[BK * NEXP]; // k-major, quad-swizzled: [kk][64 experts]

    const int tid = threadIdx.x;
    const int tg = tid & 15;        // token-pair id -> tokens {2tg, 2tg+1}
    const int eg = tid >> 4;        // expert-quad id -> experts {4eg..4eg+3}
    const int tok0 = blockIdx.x * BM;

    // staging roles: row sr (0..31), col-quad sq (0..7)
    const int sr = tid >> 3;
    const int sq = tid & 7;
    const float* xsrc  = x + (size_t)(tok0 + sr) * DDIM + 4 * sq;
    const float* wsrc0 = W + (size_t)sr * DDIM + 4 * sq;
    const float* wsrc1 = W + (size_t)(sr + 32) * DDIM + 4 * sq;

    // Precomputed LDS byte offsets for compute reads (c = kk & 15)
    int xoff[16], woff[16];
#pragma unroll
    for (int c = 0; c < 16; ++c) {
        xoff[c] = c * (BM * 4) + 8 * (tg ^ c);
        woff[c] = c * (NEXP * 4) + 16 * (eg ^ c);
    }

    float acc[2][4];
#pragma unroll
    for (int i = 0; i < 2; ++i)
#pragma unroll
        for (int j = 0; j < 4; ++j) acc[i][j] = 0.f;

    // preload chunk 0
    float4 px0 = *(const float4*)(xsrc);
    float4 px1 = *(const float4*)(xsrc + 32);
    float4 pw00 = *(const float4*)(wsrc0);
    float4 pw01 = *(const float4*)(wsrc0 + 32);
    float4 pw10 = *(const float4*)(wsrc1);
    float4 pw11 = *(const float4*)(wsrc1 + 32);

    for (int ch = 0; ch < NCH; ++ch) {
        __syncthreads();   // previous chunk's LDS reads finished
        // --- store staged regs to LDS (transposed to k-major, swizzled) ---
#pragma unroll
        for (int m = 0; m < 4; ++m) {
            const int kkA = 4 * sq + m;
            const int kkB = kkA + 32;
            xs[kkA * BM + ((sr & 1) + 2 * ((sr >> 1) ^ (kkA & 15)))] = ((const float*)&px0)[m];
            xs[kkB * BM + ((sr & 1) + 2 * ((sr >> 1) ^ (kkB & 15)))] = ((const float*)&px1)[m];
            wsh[kkA * NEXP + ((sr & 3) + 4 * ((sr >> 2) ^ (kkA & 15)))] = ((const float*)&pw00)[m];
            wsh[kkB * NEXP + ((sr & 3) + 4 * ((sr >> 2) ^ (kkB & 15)))] = ((const float*)&pw01)[m];
            wsh[kkA * NEXP + (((sr + 32) & 3) + 4 * (((sr + 32) >> 2) ^ (kkA & 15)))] = ((const float*)&pw10)[m];
            wsh[kkB * NEXP + (((sr + 32) & 3) + 4 * (((sr + 32) >> 2) ^ (kkB & 15)))] = ((const float*)&pw11)[m];
        }
        __syncthreads();
        // --- issue next chunk's global loads (overlap with compute) ---
        if (ch + 1 < NCH) {
            const int k0 = (ch + 1) * BK;
            px0 = *(const float4*)(xsrc + k0);
            px1 = *(const float4*)(xsrc + k0 + 32);
            pw00 = *(const float4*)(wsrc0 + k0);
            pw01 = *(const float4*)(wsrc0 + k0 + 32);
            pw10 = *(const float4*)(wsrc1 + k0);
            pw11 = *(const float4*)(wsrc1 + k0 + 32);
        }
        // --- compute: 64 kk iterations, zero per-iter address math ---
        const char* xb = (const char*)xs;
        const char* wb = (const char*)wsh;
#pragma unroll
        for (int rep = 0; rep < 4; ++rep) {
#pragma unroll
            for (int c = 0; c < 16; ++c) {
                const float2 xv = *(const float2*)(xb + rep * (16 * BM * 4) + xoff[c]);
                const float4 wv = *(const float4*)(wb + rep * (16 * NEXP * 4) + woff[c]);
                acc[0][0] = fmaf(xv.x, wv.x, acc[0][0]);
                acc[0][1] = fmaf(xv.x, wv.y, acc[0][1]);
                acc[0][2] = fmaf(xv.x, wv.z, acc[0][2]);
                acc[0][3] = fmaf(xv.x, wv.w, acc[0][3]);
                acc[1][0] = fmaf(xv.y, wv.x, acc[1][0]);
                acc[1][1] = fmaf(xv.y, wv.y, acc[1][1]);
                acc[1][2] = fmaf(xv.y, wv.z, acc[1][2]);
                acc[1][3] = fmaf(xv.y, wv.w, acc[1][3]);
            }
        }
    }

    // ---------------- epilogue: gather per-token logits, top-k ----------------
    __syncthreads();
    float* sc = wsh;   // reuse as [32][68] logit table (2176 floats <= 4096)
#pragma unroll
    for (int i = 0; i < 2; ++i)
#pragma unroll
        for (int j = 0; j < 4; ++j)
            sc[(2 * tg + i) * 68 + (4 * eg + j)] = acc[i][j];
    __syncthreads();

    if (tid < BM) {
        const int t = tok0 + tid;
        float val[7]; int idx[7];
#pragma unroll
        for (int p = 0; p < 7; ++p) { val[p] = -1e30f; idx[p] = 0; }
        for (int e = 0; e < NEXP; ++e) {
            const float l = sc[tid * 68 + e];
            const float s = 1.f / (1.f + expf(-l));
            float v = s + gb[e];   // biased score (fp32 rounding like ref)
            int id = e;
#pragma unroll
            for (int p = 0; p < 7; ++p) {   // stable insertion (strict >)
                const bool gt = v > val[p];
                const float ov = val[p]; const int oi = idx[p];
                val[p] = gt ? v : ov;  idx[p] = gt ? id : oi;
                v = gt ? ov : v;       id = gt ? oi : id;
            }
        }
        bool flag = false;
#pragma unroll
        for (int p = 0; p < 6; ++p) flag = flag || (val[p] - val[p + 1] < THETA);

        float s6[6]; float sum = 0.f;
#pragma unroll
        for (int p = 0; p < 6; ++p) {
            const float l = sc[tid * 68 + idx[p]];
            s6[p] = 1.f / (1.f + expf(-l));   // original (unbiased) score
            sum += s6[p];
        }
#pragma unroll
        for (int p = 0; p < 6; ++p)
            out[(size_t)t * 6 + p] = s6[p] / sum * 2.5f;

        float* oi = out + (size_t)M * 6 + (size_t)t * 8;
        oi[0] = 0.f; oi[1] = 1.f;   // shared experts
#pragma unroll
        for (int p = 0; p < 6; ++p) oi[2 + p] = (float)(idx[p] + 2);

        if (flag && wsc) {
            const int pos = atomicAdd(wsc, 1);
            if (pos < MAXFLAG) wsc[1 + pos] = t;
        }
    }
}

// ---------------------------------------------------------------------------
// Kernel 2: f64 refine of flagged tokens. One block per token; 4 waves x 16
// experts; coalesced float4 loads; exact fp32 products accumulated in f64.
// ---------------------------------------------------------------------------
__launch_bounds__(256, 2)
__global__ void gate_refine(const float* __restrict__ x, const float* __restrict__ W,
                            const float* __restrict__ gb, float* __restrict__ out,
                            const int* __restrict__ wsc, int M) {
    __shared__ double lg[NEXP];
    int cnt = wsc[0];
    if (cnt > MAXFLAG) cnt = MAXFLAG;
    const int wv = threadIdx.x >> 6;
    const int lane = threadIdx.x & 63;

    for (int i = blockIdx.x; i < cnt; i += gridDim.x) {
        const int t = wsc[1 + i];
        const float* xr = x + (size_t)t * DDIM;
        for (int ee = 0; ee < 16; ++ee) {
            const int e = wv * 16 + ee;
            const float* wr = W + (size_t)e * DDIM;
            double a0 = 0, a1 = 0, a2 = 0, a3 = 0;
#pragma unroll
            for (int it = 0; it < DDIM / 256; ++it) {
                const float4 xv = *(const float4*)(xr + it * 256 + lane * 4);
                const float4 wvv = *(const float4*)(wr + it * 256 + lane * 4);
                a0 = fma((double)xv.x, (double)wvv.x, a0);
                a1 = fma((double)xv.y, (double)wvv.y, a1);
                a2 = fma((double)xv.z, (double)wvv.z, a2);
                a3 = fma((double)xv.w, (double)wvv.w, a3);
            }
            double s = (a0 + a1) + (a2 + a3);
#pragma unroll
            for (int o = 32; o > 0; o >>= 1) s += __shfl_down(s, o, 64);
            if (lane == 0) lg[e] = s;
        }
        __syncthreads();
        if (threadIdx.x < NEXP) {   // lane-parallel sigmoid + bias (f64)
            const double l = lg[threadIdx.x];
            lg[threadIdx.x] = 1.0 / (1.0 + exp(-l)) + (double)gb[threadIdx.x];
        }
        __syncthreads();
        if (threadIdx.x == 0) {
            double val[7]; int idx[7];
#pragma unroll
            for (int p = 0; p < 7; ++p) { val[p] = -1e30; idx[p] = 0; }
            for (int e = 0; e < NEXP; ++e) {
                double v = lg[e]; int id = e;
#pragma unroll
                for (int p = 0; p < 7; ++p) {
                    const bool gt = v > val[p];
                    const double ov = val[p]; const int oi2 = idx[p];
                    val[p] = gt ? v : ov; idx[p] = gt ? id : oi2;
                    v = gt ? ov : v;      id = gt ? oi2 : id;
                }
            }
            double s6[6], sum = 0.0;
#pragma unroll
            for (int p = 0; p < 6; ++p) { s6[p] = val[p] - (double)gb[idx[p]]; sum += s6[p]; }
#pragma unroll
            for (int p = 0; p < 6; ++p)
                out[(size_t)t * 6 + p] = (float)(s6[p] / sum * 2.5);
            float* oi = out + (size_t)M * 6 + (size_t)t * 8;
            oi[0] = 0.f; oi[1] = 1.f;
#pragma unroll
            for (int p = 0; p < 6; ++p) oi[2 + p] = (float)(idx[p] + 2);
        }
        __syncthreads();
    }
}

extern "C" void kernel_launch(void* const* d_in, const int* in_sizes, int n_in,
                              void* d_out, int out_size, void* d_ws, size_t ws_size,
                              hipStream_t stream) {
    const float* x = (const float*)d_in[0];
    const float* W = (const float*)d_in[1];
    const float* gb = (const float*)d_in[2];
    float* out = (float*)d_out;
    const int M = in_sizes[0] / DDIM;   // 16384

    const bool refine_ok = ws_size >= (size_t)(1 + MAXFLAG) * sizeof(int);
    int* wsc = refine_ok ? (int*)d_ws : (int*)nullptr;
    if (refine_ok) hipMemsetAsync(d_ws, 0, sizeof(int), stream);

    hipLaunchKernelGGL(gate_main, dim3(M / BM), dim3(256), 0, stream,
                       x, W, gb, out, wsc, M);
    if (refine_ok)
        hipLaunchKernelGGL(gate_refine, dim3(256), dim3(256), 0, stream,
                           x, W, gb, out, wsc, M);
}